// Round 1
// 327.936 us; speedup vs baseline: 1.0498x; 1.0498x over previous
//
#include <hip/hip_runtime.h>

#define SEQ   1024
#define BATCH 512
#define NC    48
#define CH    8

typedef float f2 __attribute__((ext_vector_type(2)));
typedef float f4 __attribute__((ext_vector_type(4)));

__device__ __forceinline__ float rfl(float x) {
    return __int_as_float(__builtin_amdgcn_readfirstlane(__float_as_int(x)));
}
__device__ __forceinline__ float rlane(float x, int l) {
    return __int_as_float(__builtin_amdgcn_readlane(__float_as_int(x), l));
}
// packed fp32 FMA: acc.lo += a.lo*b.lo ; acc.hi += a.hi*b.hi
__device__ __forceinline__ void pkfma(f2& acc, f2 a, f2 b) {
    asm("v_pk_fma_f32 %0, %1, %2, %0" : "+v"(acc) : "v"(a), "v"(b));
}

// One wave per batch element. Lane j owns state j (j<48).
//
// R6 redesign (vs R5 readlane-only): per-step critical path was 549 cy of
// which only ~170 was VALU issue. Changes:
//  - broadcast split across two pipes: i=0..23 via 24 readlane + 24 scalar
//    FMA (VALU), i=24..47 via ds_write + 6 same-address ds_read_b128 feeding
//    12 v_pk_fma_f32 (LDS latency overlaps the readlane stream; pk halves
//    that half's FMA issue).
//  - esm = exp2(s*log2e) precomputed per chunk from prefetched scores —
//    removes the z-dependent rfl->cvt->fma->exp chain from every step.
//  - exact pow2 rescale (z *= 2^-ex, S += ex; logZ-invariant even on frozen
//    lanes) only every 4 steps instead of per-step.
//  - main loop runs unguarded full chunks (t0+8 <= L); one guarded tail.
__global__ __launch_bounds__(64, 1) void crf_fwd(
    const float* __restrict__ scores,   // [SEQ][BATCH][NC]
    const int*   __restrict__ target,   // [SEQ][BATCH]
    const int*   __restrict__ lengths,  // [BATCH]
    const float* __restrict__ trans,    // [NC][NC]
    float* __restrict__ out)            // [2*BATCH]: X, then X - logZ
{
    const int b    = blockIdx.x;
    const int lane = threadIdx.x;
    const int jc   = (lane < NC) ? lane : (NC - 1);   // lanes 48-63 mirror col 47 (never read)
    const int L    = lengths[b];                       // uniform within block
    const float LOG2E = 1.4426950408889634f;
    const float LN2   = 0.6931471805599453f;
    const size_t TS = (size_t)BATCH * NC;
    const float* sp = scores + (size_t)b * NC + jc;

    __shared__ __align__(16) float zbuf[64];

    // ---- register staging buffers + first two chunks in flight ----
    float A[CH], B[CH];
    #define PREFETCH(buf, tbase) do { \
        _Pragma("unroll") \
        for (int k_ = 0; k_ < CH; ++k_) { \
            int tt_ = (tbase) + k_; if (tt_ > SEQ - 1) tt_ = SEQ - 1; \
            (buf)[k_] = sp[(size_t)tt_ * TS]; \
        } } while (0)
    PREFETCH(A, 0);
    PREFETCH(B, CH);

    // ---- target path score X (parallel over t, then reduce) ----
    float x = 0.f;
    #pragma unroll 4
    for (int t = lane; t < L; t += 64) {
        int cur = target[t * BATCH + b];
        float e = scores[(size_t)t * TS + (size_t)b * NC + cur];
        float tr = 0.f;
        if (t > 0) {
            int prev = target[(t - 1) * BATCH + b];
            tr = trans[prev * NC + cur];
        }
        x += e + tr;
    }
    #pragma unroll
    for (int k = 32; k >= 1; k >>= 1) x += __shfl_xor(x, k, 64);

    // ---- E = exp(T) column jc. Scalars for i=0..23, packed pairs 24..47 ----
    #define DECLE(i) float e##i = __builtin_amdgcn_exp2f(trans[(i)*NC + jc] * LOG2E); \
                     asm("" : "+v"(e##i));
    DECLE(0)  DECLE(1)  DECLE(2)  DECLE(3)  DECLE(4)  DECLE(5)  DECLE(6)  DECLE(7)
    DECLE(8)  DECLE(9)  DECLE(10) DECLE(11) DECLE(12) DECLE(13) DECLE(14) DECLE(15)
    DECLE(16) DECLE(17) DECLE(18) DECLE(19) DECLE(20) DECLE(21) DECLE(22) DECLE(23)
    #undef DECLE
    #define DECLEP(m) f2 ep##m; \
        ep##m.x = __builtin_amdgcn_exp2f(trans[(24 + 2*(m))*NC + jc] * LOG2E); \
        ep##m.y = __builtin_amdgcn_exp2f(trans[(25 + 2*(m))*NC + jc] * LOG2E); \
        asm("" : "+v"(ep##m));
    DECLEP(0) DECLEP(1) DECLEP(2)  DECLEP(3)
    DECLEP(4) DECLEP(5) DECLEP(6)  DECLEP(7)
    DECLEP(8) DECLEP(9) DECLEP(10) DECLEP(11)
    #undef DECLEP

    // ---- t = 0 init (uses raw A[0], before EXP8 converts the chunk) ----
    float sv_init = A[0];
    float s00 = rfl(sv_init);
    float z = __builtin_amdgcn_exp2f((sv_init - s00) * LOG2E);
    float S = s00 * LOG2E;

    // convert a chunk of raw scores to esm = 2^(s*log2e) = e^s  (off z-chain)
    #define EXP8(buf) do { _Pragma("unroll") \
        for (int k_ = 0; k_ < CH; ++k_) (buf)[k_] = __builtin_amdgcn_exp2f((buf)[k_] * LOG2E); } while (0)
    EXP8(A);

    // exact pow2 rescale every 4 steps: logZ-invariant, safe on frozen lanes
    #define RS() do { \
        int eb_ = (__builtin_amdgcn_readfirstlane(__float_as_int(z)) >> 23) & 255; \
        z *= __int_as_float((254 - eb_) << 23); \
        S += (float)(eb_ - 127); \
    } while (0)

    // 8 readlane-broadcasts + 8 SGPR*VGPR FMAs
    #define G8(l0,l1,l2,l3,l4,l5,l6,l7, ea,eb,ec,ed,ee,ef,eg,eh) { \
        float s0_=rlane(z,l0), s1_=rlane(z,l1), s2_=rlane(z,l2), s3_=rlane(z,l3); \
        float s4_=rlane(z,l4), s5_=rlane(z,l5), s6_=rlane(z,l6), s7_=rlane(z,l7); \
        a0=fmaf(s0_,ea,a0); a1=fmaf(s1_,eb,a1); a2=fmaf(s2_,ec,a2); a3=fmaf(s3_,ed,a3); \
        a4=fmaf(s4_,ee,a4); a5=fmaf(s5_,ef,a5); a6=fmaf(s6_,eg,a6); a7=fmaf(s7_,eh,a7); }

    // one recurrence step: hybrid broadcast (readlane half + LDS/pk half)
    #define STEP_CORE(esmv, ZUPD) do { \
        zbuf[lane] = z; \
        asm volatile("" ::: "memory");  /* keep reads after the write */ \
        f4 q0 = *(const f4*)&zbuf[24]; \
        f4 q1 = *(const f4*)&zbuf[28]; \
        f4 q2 = *(const f4*)&zbuf[32]; \
        f4 q3 = *(const f4*)&zbuf[36]; \
        f4 q4 = *(const f4*)&zbuf[40]; \
        f4 q5 = *(const f4*)&zbuf[44]; \
        float a0=0.f,a1=0.f,a2=0.f,a3=0.f,a4=0.f,a5=0.f,a6=0.f,a7=0.f; \
        G8( 0, 1, 2, 3, 4, 5, 6, 7,  e0 ,e1 ,e2 ,e3 ,e4 ,e5 ,e6 ,e7 ) \
        G8( 8, 9,10,11,12,13,14,15,  e8 ,e9 ,e10,e11,e12,e13,e14,e15) \
        G8(16,17,18,19,20,21,22,23,  e16,e17,e18,e19,e20,e21,e22,e23) \
        f2 k0={0.f,0.f}, k1={0.f,0.f}, k2={0.f,0.f}, k3={0.f,0.f}; \
        { f2 p_; \
          p_.x=q0.x; p_.y=q0.y; pkfma(k0,p_,ep0); \
          p_.x=q0.z; p_.y=q0.w; pkfma(k1,p_,ep1); \
          p_.x=q1.x; p_.y=q1.y; pkfma(k2,p_,ep2); \
          p_.x=q1.z; p_.y=q1.w; pkfma(k3,p_,ep3); \
          p_.x=q2.x; p_.y=q2.y; pkfma(k0,p_,ep4); \
          p_.x=q2.z; p_.y=q2.w; pkfma(k1,p_,ep5); \
          p_.x=q3.x; p_.y=q3.y; pkfma(k2,p_,ep6); \
          p_.x=q3.z; p_.y=q3.w; pkfma(k3,p_,ep7); \
          p_.x=q4.x; p_.y=q4.y; pkfma(k0,p_,ep8); \
          p_.x=q4.z; p_.y=q4.w; pkfma(k1,p_,ep9); \
          p_.x=q5.x; p_.y=q5.y; pkfma(k2,p_,ep10); \
          p_.x=q5.z; p_.y=q5.w; pkfma(k3,p_,ep11); \
        } \
        f2 kk = (k0+k1)+(k2+k3); \
        float sum_ = (((a0+a4)+(a1+a5)) + ((a2+a6)+(a3+a7))) + (kk.x + kk.y); \
        float znew_ = sum_ * (esmv); \
        ZUPD; \
    } while (0)

    #define STEPU(buf, sidx)      STEP_CORE((buf)[sidx], z = znew_)
    #define STEPG(buf, sidx, tb)  STEP_CORE((buf)[sidx], if (((tb)+(sidx)) < L) z = znew_)

    #define CHUNK8U(buf) do { \
        STEPU(buf,0); STEPU(buf,1); STEPU(buf,2); STEPU(buf,3); RS(); \
        STEPU(buf,4); STEPU(buf,5); STEPU(buf,6); STEPU(buf,7); RS(); \
    } while (0)
    #define CHUNK8G(buf, tb) do { \
        STEPG(buf,0,tb); STEPG(buf,1,tb); STEPG(buf,2,tb); STEPG(buf,3,tb); RS(); \
        STEPG(buf,4,tb); STEPG(buf,5,tb); STEPG(buf,6,tb); STEPG(buf,7,tb); RS(); \
    } while (0)

    // prologue: steps 1..7 from chunk 0 (guarded; L may be small)
    STEPG(A,1,0); STEPG(A,2,0); STEPG(A,3,0); RS();
    STEPG(A,4,0); STEPG(A,5,0); STEPG(A,6,0); STEPG(A,7,0); RS();

    // main: unguarded full chunks; prefetch next chunk before processing current
    int t0 = CH;
    int useB = 1;
    while (t0 + CH <= L) {
        if (useB) { PREFETCH(A, t0 + CH); EXP8(B); CHUNK8U(B); }
        else      { PREFETCH(B, t0 + CH); EXP8(A); CHUNK8U(A); }
        useB ^= 1;
        t0 += CH;
    }
    // guarded tail chunk (covers t0 .. L-1)
    if (t0 < L) {
        if (useB) { EXP8(B); CHUNK8G(B, t0); }
        else      { EXP8(A); CHUNK8G(A, t0); }
    }

    #undef STEP_CORE
    #undef STEPU
    #undef STEPG
    #undef CHUNK8U
    #undef CHUNK8G
    #undef G8
    #undef RS
    #undef EXP8
    #undef PREFETCH

    // ---- finalize: logZ = ln2 * (log2(sum_j z_j) + S) ----
    float zs = (lane < NC) ? z : 0.f;
    #pragma unroll
    for (int k = 32; k >= 1; k >>= 1) zs += __shfl_xor(zs, k, 64);
    float logZ = (__builtin_amdgcn_logf(zs) + S) * LN2;

    if (lane == 0) {
        out[b]         = x;          // output 0: X
        out[BATCH + b] = x - logZ;   // output 1: X - logZ
    }
}

extern "C" void kernel_launch(void* const* d_in, const int* in_sizes, int n_in,
                              void* d_out, int out_size, void* d_ws, size_t ws_size,
                              hipStream_t stream) {
    const float* scores  = (const float*)d_in[0];
    const int*   target  = (const int*)d_in[1];
    const int*   lengths = (const int*)d_in[2];
    const float* trans   = (const float*)d_in[3];
    float* out = (float*)d_out;
    crf_fwd<<<BATCH, 64, 0, stream>>>(scores, target, lengths, trans, out);
}